// Round 2
// baseline (952.330 us; speedup 1.0000x reference)
//
#include <hip/hip_runtime.h>
#include <hip/hip_bf16.h>

#define NN 100000
#define NE 3200000
#define NF 512
#define NH 16
#define NC 40
#define NB 782          // ceil(NN/128) buckets of 128 nodes
#define CAP 5120        // max edges per bucket (mean 4096, std 64)

typedef __attribute__((ext_vector_type(4))) float f32x4;
typedef __attribute__((ext_vector_type(8))) short bf16x8;

static __device__ __forceinline__ unsigned short f2b(float f) {
    unsigned int u = __float_as_uint(f);
    u += 0x7FFFu + ((u >> 16) & 1u);   // round-to-nearest-even
    return (unsigned short)(u >> 16);
}

// ---------------- CSR build: two-level counting sort ----------------

__global__ void __launch_bounds__(256) k_bcount(const int* __restrict__ ei,
                                                int* __restrict__ bcnt) {
    __shared__ int h[NB];
    for (int i = threadIdx.x; i < NB; i += 256) h[i] = 0;
    __syncthreads();
    int stride = gridDim.x * 256;
    for (int e = blockIdx.x * 256 + threadIdx.x; e < NE; e += stride)
        atomicAdd(&h[((unsigned)ei[NE + e]) >> 7], 1);
    __syncthreads();
    for (int i = threadIdx.x; i < NB; i += 256)
        if (h[i]) atomicAdd(&bcnt[i], h[i]);
}

__global__ void k_bscan(const int* __restrict__ bcnt, int* __restrict__ bptr,
                        int* __restrict__ bfill, int* __restrict__ rowptr) {
    __shared__ int sh[1024];
    int t = threadIdx.x;
    int v = (t < NB) ? bcnt[t] : 0;
    sh[t] = v;
    __syncthreads();
    for (int off = 1; off < 1024; off <<= 1) {
        int add = (t >= off) ? sh[t - off] : 0;
        __syncthreads();
        sh[t] += add;
        __syncthreads();
    }
    if (t < NB) { int e = sh[t] - v; bptr[t] = e; bfill[t] = e; }
    if (t == 0) { bptr[NB] = NE; rowptr[NN] = NE; }
}

__global__ void __launch_bounds__(256) k_bscatter(const int* __restrict__ ei,
                                                  int* __restrict__ bfill,
                                                  unsigned int* __restrict__ pairs) {
    int e = blockIdx.x * 256 + threadIdx.x;
    if (e < NE) {
        unsigned int s = (unsigned int)ei[e];
        unsigned int d = (unsigned int)ei[NE + e];
        int pos = atomicAdd(&bfill[d >> 7], 1);
        pairs[pos] = s | ((d & 127u) << 17);
    }
}

__global__ void __launch_bounds__(256) k_bsort(const unsigned int* __restrict__ pairs,
                                               const int* __restrict__ bptr,
                                               int* __restrict__ rowptr,
                                               float* __restrict__ dinv,
                                               int* __restrict__ ssrc) {
    __shared__ unsigned int ein[CAP];
    __shared__ unsigned int srt[CAP];
    __shared__ int lcnt[128], lofs[128], lcur[128];
    int b = blockIdx.x;
    int s0 = bptr[b], s1 = bptr[b + 1];
    int n = s1 - s0;
    for (int i = threadIdx.x; i < n; i += 256) ein[i] = pairs[s0 + i];
    if (threadIdx.x < 128) lcnt[threadIdx.x] = 0;
    __syncthreads();
    for (int i = threadIdx.x; i < n; i += 256) atomicAdd(&lcnt[ein[i] >> 17], 1);
    __syncthreads();
    if (threadIdx.x < 128) lofs[threadIdx.x] = lcnt[threadIdx.x];
    __syncthreads();
    for (int off = 1; off < 128; off <<= 1) {
        int add = 0;
        if (threadIdx.x < 128 && threadIdx.x >= off) add = lofs[threadIdx.x - off];
        __syncthreads();
        if (threadIdx.x < 128) lofs[threadIdx.x] += add;
        __syncthreads();
    }
    if (threadIdx.x < 128) {
        int excl = lofs[threadIdx.x] - lcnt[threadIdx.x];
        lcur[threadIdx.x] = excl;
        int node = b * 128 + threadIdx.x;
        if (node < NN) {
            rowptr[node] = s0 + excl;
            dinv[node] = rsqrtf((float)(lcnt[threadIdx.x] + 1));
        }
    }
    __syncthreads();
    for (int i = threadIdx.x; i < n; i += 256) {
        unsigned int v = ein[i];
        int pos = atomicAdd(&lcur[v >> 17], 1);
        srt[pos] = v & 0x1FFFFu;
    }
    __syncthreads();
    for (int i = threadIdx.x; i < n; i += 256) ssrc[s0 + i] = (int)srt[i];
}

// ---------------- W1 pack (per-lane MFMA B-fragment layout, f32 -> bf16) ----------------
// idx = (s*64 + l)*8 + e  holds  W1[32*s + (l>>4)*8 + e][l&15]

__global__ void k_packW1(const float* __restrict__ W1, unsigned short* __restrict__ pack) {
    int idx = blockIdx.x * 256 + threadIdx.x;   // 16*64*8 = 8192 total
    int s = idx >> 9;
    int l = (idx >> 3) & 63;
    int e = idx & 7;
    int k = s * 32 + (l >> 4) * 8 + e;
    int col = l & 15;
    pack[idx] = f2b(W1[k * 16 + col]);
}

// ---------------- GEMM1: hs1 = (X @ W1) * dinv[:,None]  (bf16 MFMA) ----------------

__global__ void __launch_bounds__(256) k_gemm1(const float* __restrict__ x,
                                               const unsigned short* __restrict__ wp,
                                               const float* __restrict__ dinv,
                                               float* __restrict__ hs1) {
    int wave = threadIdx.x >> 6;
    int l = threadIdx.x & 63;
    int m0 = blockIdx.x * 64 + wave * 16;
    if (m0 >= NN) return;                        // NN % 16 == 0
    int row = m0 + (l & 15);
    int krow = (l >> 4) * 8;
    const float* xr = x + (size_t)row * NF + krow;
    const unsigned short* wl = wp + l * 8;

    f32x4 acc = {0.f, 0.f, 0.f, 0.f};
#pragma unroll 4
    for (int s = 0; s < 16; ++s) {
        f32x4 xa = *(const f32x4*)(xr + s * 32);
        f32x4 xb = *(const f32x4*)(xr + s * 32 + 4);
        union { bf16x8 v; unsigned short u[8]; } a;
        a.u[0] = f2b(xa.x); a.u[1] = f2b(xa.y); a.u[2] = f2b(xa.z); a.u[3] = f2b(xa.w);
        a.u[4] = f2b(xb.x); a.u[5] = f2b(xb.y); a.u[6] = f2b(xb.z); a.u[7] = f2b(xb.w);
        bf16x8 b = *(const bf16x8*)(wl + s * 512);
        acc = __builtin_amdgcn_mfma_f32_16x16x32_bf16(a.v, b, acc, 0, 0, 0);
    }
    // C layout: col = l&15, row = (l>>4)*4 + r
#pragma unroll
    for (int r = 0; r < 4; ++r) {
        int orow = m0 + (l >> 4) * 4 + r;
        hs1[(size_t)orow * NH + (l & 15)] = acc[r] * dinv[orow];
    }
}

// ---------------- Aggregation over pre-scaled features ----------------
// in:  hs[i] = h[i] * dinv[i]
// acc = sum_{src->i} hs[src] + hs[i]           (self-loop)
// do_relu: out = relu(acc*dinv[i] + bias) * dinv[i]   (feeds next gather)
// else:    out = acc*dinv[i]

__global__ void __launch_bounds__(256) k_agg(const float* __restrict__ hs,
                                             const int* __restrict__ rowptr,
                                             const int* __restrict__ ssrc,
                                             const float* __restrict__ dinv,
                                             const float* __restrict__ bias,
                                             float* __restrict__ hout, int do_relu) {
    int l = threadIdx.x & 63;
    int node = blockIdx.x * 4 + (threadIdx.x >> 6);
    if (node >= NN) return;
    int j = l & 15;
    int ec = l >> 4;
    float di = dinv[node];
    int s = rowptr[node];
    int epos = rowptr[node + 1];
    float acc = (ec == 0) ? hs[(size_t)node * NH + j] : 0.0f;
#pragma unroll 4
    for (int e = s + ec; e < epos; e += 4) {
        int src = ssrc[e];
        acc += hs[(size_t)src * NH + j];
    }
    acc += __shfl_xor(acc, 16, 64);
    acc += __shfl_xor(acc, 32, 64);
    if (ec == 0) {
        float o = acc * di;
        if (do_relu) o = fmaxf(o + bias[j], 0.0f) * di;
        hout[(size_t)node * NH + j] = o;
    }
}

// ---------------- Final: out = log_softmax(z2 @ W2 + b2) ----------------

__global__ void __launch_bounds__(256) k_out(const float* __restrict__ z2,
                                             const float* __restrict__ W2,
                                             const float* __restrict__ b2,
                                             float* __restrict__ out) {
    __shared__ float w[NH * NC];
    __shared__ float bb[NC];
    for (int i = threadIdx.x; i < NH * NC; i += 256) w[i] = W2[i];
    if (threadIdx.x < NC) bb[threadIdx.x] = b2[threadIdx.x];
    __syncthreads();
    int node = blockIdx.x * 256 + threadIdx.x;
    if (node >= NN) return;
    float z[NH];
    const f32x4* zp = (const f32x4*)(z2 + (size_t)node * NH);
#pragma unroll
    for (int q = 0; q < 4; ++q) {
        f32x4 v = zp[q];
        z[q * 4 + 0] = v.x; z[q * 4 + 1] = v.y; z[q * 4 + 2] = v.z; z[q * 4 + 3] = v.w;
    }
    float logit[NC];
#pragma unroll
    for (int c = 0; c < NC; ++c) logit[c] = bb[c];
#pragma unroll
    for (int k = 0; k < NH; ++k) {
        float zv = z[k];
#pragma unroll
        for (int c = 0; c < NC; ++c) logit[c] += zv * w[k * NC + c];
    }
    float mx = logit[0];
#pragma unroll
    for (int c = 1; c < NC; ++c) mx = fmaxf(mx, logit[c]);
    float sum = 0.f;
#pragma unroll
    for (int c = 0; c < NC; ++c) sum += __expf(logit[c] - mx);
    float lse = mx + __logf(sum);
    float* op = out + (size_t)node * NC;
#pragma unroll
    for (int c = 0; c < NC; ++c) op[c] = logit[c] - lse;
}

// ---------------- launch ----------------

extern "C" void kernel_launch(void* const* d_in, const int* in_sizes, int n_in,
                              void* d_out, int out_size, void* d_ws, size_t ws_size,
                              hipStream_t stream) {
    const float* x  = (const float*)d_in[0];
    const int*   ei = (const int*)d_in[1];
    const float* W1 = (const float*)d_in[2];
    const float* b1 = (const float*)d_in[3];
    const float* W2 = (const float*)d_in[4];
    const float* b2 = (const float*)d_in[5];
    float* out = (float*)d_out;

    char* ws = (char*)d_ws;
    size_t off = 0;
    auto alloc = [&](size_t bytes) -> void* {
        void* p = ws + off;
        off += (bytes + 255) & ~(size_t)255;
        return p;
    };
    int* bcnt       = (int*)alloc((size_t)NB * 4);
    int* bptr       = (int*)alloc((size_t)(NB + 1) * 4);
    int* bfill      = (int*)alloc((size_t)NB * 4);
    int* rowptr     = (int*)alloc((size_t)(NN + 1) * 4);
    float* dinv     = (float*)alloc((size_t)NN * 4);
    unsigned short* w1p = (unsigned short*)alloc(16 * 64 * 8 * 2);
    unsigned int* pairs = (unsigned int*)alloc((size_t)NE * 4);
    int* ssrc       = (int*)alloc((size_t)NE * 4);
    float* h1       = (float*)alloc((size_t)NN * NH * 4);   // hs1, reused as z2
    float* r1       = (float*)alloc((size_t)NN * NH * 4);   // r1s

    int nb = (NN + 255) / 256;          // 391
    int ebl = (NE + 255) / 256;         // 12500

    hipMemsetAsync(bcnt, 0, (size_t)NB * 4, stream);
    k_packW1<<<32, 256, 0, stream>>>(W1, w1p);
    k_bcount<<<512, 256, 0, stream>>>(ei, bcnt);
    k_bscan<<<1, 1024, 0, stream>>>(bcnt, bptr, bfill, rowptr);
    k_bscatter<<<ebl, 256, 0, stream>>>(ei, bfill, pairs);
    k_bsort<<<NB, 256, 0, stream>>>(pairs, bptr, rowptr, dinv, ssrc);
    k_gemm1<<<(NN + 63) / 64, 256, 0, stream>>>(x, w1p, dinv, h1);
    k_agg<<<NN / 4, 256, 0, stream>>>(h1, rowptr, ssrc, dinv, b1, r1, 1);
    k_agg<<<NN / 4, 256, 0, stream>>>(r1, rowptr, ssrc, dinv, nullptr, h1, 0);
    k_out<<<nb, 256, 0, stream>>>(h1, W2, b2, out);
}

// Round 3
// 251.320 us; speedup vs baseline: 3.7893x; 3.7893x over previous
//
#include <hip/hip_runtime.h>
#include <hip/hip_bf16.h>

#define NN 100000
#define NE 3200000
#define NF 512
#define NH 16
#define NC 40
#define NB 782          // ceil(NN/128) buckets of 128 nodes
#define CAP 5120        // max edges per bucket (mean 4096, std 64)
#define NBLK 512        // multisplit blocks
#define CHUNK 6250      // NE / NBLK

typedef __attribute__((ext_vector_type(4))) float f32x4;
typedef __attribute__((ext_vector_type(8))) short bf16x8;

static __device__ __forceinline__ unsigned short f2b(float f) {
    unsigned int u = __float_as_uint(f);
    u += 0x7FFFu + ((u >> 16) & 1u);   // round-to-nearest-even
    return (unsigned short)(u >> 16);
}

// ---------------- multisplit pass 1: per-block bucket histograms ----------------

__global__ void __launch_bounds__(256) k_mshist(const int* __restrict__ ei,
                                                int* __restrict__ histG) {
    __shared__ int h[NB];
    for (int i = threadIdx.x; i < NB; i += 256) h[i] = 0;
    __syncthreads();
    int b = blockIdx.x;
    int e0 = b * CHUNK, e1 = min(NE, e0 + CHUNK);
    for (int e = e0 + threadIdx.x; e < e1; e += 256)
        atomicAdd(&h[((unsigned)ei[NE + e]) >> 7], 1);
    __syncthreads();
    for (int i = threadIdx.x; i < NB; i += 256)
        histG[b * NB + i] = h[i];    // coalesced row write
}

// ---------------- pass 2: per-bucket scan over blocks ----------------

__global__ void __launch_bounds__(512) k_colscan(const int* __restrict__ histG,
                                                 int* __restrict__ ofsG,
                                                 int* __restrict__ bcnt) {
    __shared__ int sh[NBLK];
    int k = blockIdx.x;          // bucket
    int t = threadIdx.x;         // block index
    int v = histG[t * NB + k];   // strided read (L2-resident table)
    sh[t] = v;
    __syncthreads();
    for (int off = 1; off < NBLK; off <<= 1) {
        int add = (t >= off) ? sh[t - off] : 0;
        __syncthreads();
        sh[t] += add;
        __syncthreads();
    }
    ofsG[k * NBLK + t] = sh[t] - v;   // exclusive, coalesced write
    if (t == NBLK - 1) bcnt[k] = sh[t];
}

// ---------------- pass 3: scan bucket totals ----------------

__global__ void k_bscan(const int* __restrict__ bcnt, int* __restrict__ bptr,
                        int* __restrict__ rowptr) {
    __shared__ int sh[1024];
    int t = threadIdx.x;
    int v = (t < NB) ? bcnt[t] : 0;
    sh[t] = v;
    __syncthreads();
    for (int off = 1; off < 1024; off <<= 1) {
        int add = (t >= off) ? sh[t - off] : 0;
        __syncthreads();
        sh[t] += add;
        __syncthreads();
    }
    if (t < NB) bptr[t] = sh[t] - v;
    if (t == 0) { bptr[NB] = NE; rowptr[NN] = NE; }
}

// ---------------- pass 4: scatter via LDS cursors (no global atomics) ----------------

__global__ void __launch_bounds__(256) k_msscatter(const int* __restrict__ ei,
                                                   const int* __restrict__ bptr,
                                                   const int* __restrict__ ofsG,
                                                   unsigned int* __restrict__ pairs) {
    __shared__ int lcur[NB];
    int b = blockIdx.x;
    for (int k = threadIdx.x; k < NB; k += 256)
        lcur[k] = bptr[k] + ofsG[k * NBLK + b];
    __syncthreads();
    int e0 = b * CHUNK, e1 = min(NE, e0 + CHUNK);
    for (int e = e0 + threadIdx.x; e < e1; e += 256) {
        unsigned int s = (unsigned int)ei[e];
        unsigned int d = (unsigned int)ei[NE + e];
        int pos = atomicAdd(&lcur[d >> 7], 1);
        pairs[pos] = s | ((d & 127u) << 17);
    }
}

// ---------------- per-bucket counting sort -> CSR ----------------

__global__ void __launch_bounds__(256) k_bsort(const unsigned int* __restrict__ pairs,
                                               const int* __restrict__ bptr,
                                               int* __restrict__ rowptr,
                                               float* __restrict__ dinv,
                                               int* __restrict__ ssrc) {
    __shared__ unsigned int ein[CAP];
    __shared__ unsigned int srt[CAP];
    __shared__ int lcnt[128], lofs[128], lcur[128];
    int b = blockIdx.x;
    int s0 = bptr[b], s1 = bptr[b + 1];
    int n = s1 - s0;
    for (int i = threadIdx.x; i < n; i += 256) ein[i] = pairs[s0 + i];
    if (threadIdx.x < 128) lcnt[threadIdx.x] = 0;
    __syncthreads();
    for (int i = threadIdx.x; i < n; i += 256) atomicAdd(&lcnt[ein[i] >> 17], 1);
    __syncthreads();
    if (threadIdx.x < 128) lofs[threadIdx.x] = lcnt[threadIdx.x];
    __syncthreads();
    for (int off = 1; off < 128; off <<= 1) {
        int add = 0;
        if (threadIdx.x < 128 && threadIdx.x >= off) add = lofs[threadIdx.x - off];
        __syncthreads();
        if (threadIdx.x < 128) lofs[threadIdx.x] += add;
        __syncthreads();
    }
    if (threadIdx.x < 128) {
        int excl = lofs[threadIdx.x] - lcnt[threadIdx.x];
        lcur[threadIdx.x] = excl;
        int node = b * 128 + threadIdx.x;
        if (node < NN) {
            rowptr[node] = s0 + excl;
            dinv[node] = rsqrtf((float)(lcnt[threadIdx.x] + 1));
        }
    }
    __syncthreads();
    for (int i = threadIdx.x; i < n; i += 256) {
        unsigned int v = ein[i];
        int pos = atomicAdd(&lcur[v >> 17], 1);
        srt[pos] = v & 0x1FFFFu;
    }
    __syncthreads();
    for (int i = threadIdx.x; i < n; i += 256) ssrc[s0 + i] = (int)srt[i];
}

// ---------------- W1 pack (per-lane MFMA B-fragment layout, f32 -> bf16) ----------------
// idx = (s*64 + l)*8 + e  holds  W1[32*s + (l>>4)*8 + e][l&15]

__global__ void k_packW1(const float* __restrict__ W1, unsigned short* __restrict__ pack) {
    int idx = blockIdx.x * 256 + threadIdx.x;   // 16*64*8 = 8192 total
    int s = idx >> 9;
    int l = (idx >> 3) & 63;
    int e = idx & 7;
    int k = s * 32 + (l >> 4) * 8 + e;
    int col = l & 15;
    pack[idx] = f2b(W1[k * 16 + col]);
}

// ---------------- GEMM1: hs1 = (X @ W1) * dinv[:,None]  (bf16 MFMA) ----------------

__global__ void __launch_bounds__(256) k_gemm1(const float* __restrict__ x,
                                               const unsigned short* __restrict__ wp,
                                               const float* __restrict__ dinv,
                                               float* __restrict__ hs1) {
    int wave = threadIdx.x >> 6;
    int l = threadIdx.x & 63;
    int m0 = blockIdx.x * 64 + wave * 16;
    if (m0 >= NN) return;                        // NN % 16 == 0
    int row = m0 + (l & 15);
    int krow = (l >> 4) * 8;
    const float* xr = x + (size_t)row * NF + krow;
    const unsigned short* wl = wp + l * 8;

    f32x4 acc = {0.f, 0.f, 0.f, 0.f};
#pragma unroll 4
    for (int s = 0; s < 16; ++s) {
        f32x4 xa = *(const f32x4*)(xr + s * 32);
        f32x4 xb = *(const f32x4*)(xr + s * 32 + 4);
        union { bf16x8 v; unsigned short u[8]; } a;
        a.u[0] = f2b(xa.x); a.u[1] = f2b(xa.y); a.u[2] = f2b(xa.z); a.u[3] = f2b(xa.w);
        a.u[4] = f2b(xb.x); a.u[5] = f2b(xb.y); a.u[6] = f2b(xb.z); a.u[7] = f2b(xb.w);
        bf16x8 b = *(const bf16x8*)(wl + s * 512);
        acc = __builtin_amdgcn_mfma_f32_16x16x32_bf16(a.v, b, acc, 0, 0, 0);
    }
    // C layout: col = l&15, row = (l>>4)*4 + r
#pragma unroll
    for (int r = 0; r < 4; ++r) {
        int orow = m0 + (l >> 4) * 4 + r;
        hs1[(size_t)orow * NH + (l & 15)] = acc[r] * dinv[orow];
    }
}

// ---------------- Aggregation over pre-scaled features ----------------

__global__ void __launch_bounds__(256) k_agg(const float* __restrict__ hs,
                                             const int* __restrict__ rowptr,
                                             const int* __restrict__ ssrc,
                                             const float* __restrict__ dinv,
                                             const float* __restrict__ bias,
                                             float* __restrict__ hout, int do_relu) {
    int l = threadIdx.x & 63;
    int node = blockIdx.x * 4 + (threadIdx.x >> 6);
    if (node >= NN) return;
    int j = l & 15;
    int ec = l >> 4;
    float di = dinv[node];
    int s = rowptr[node];
    int epos = rowptr[node + 1];
    float acc = (ec == 0) ? hs[(size_t)node * NH + j] : 0.0f;
#pragma unroll 4
    for (int e = s + ec; e < epos; e += 4) {
        int src = ssrc[e];
        acc += hs[(size_t)src * NH + j];
    }
    acc += __shfl_xor(acc, 16, 64);
    acc += __shfl_xor(acc, 32, 64);
    if (ec == 0) {
        float o = acc * di;
        if (do_relu) o = fmaxf(o + bias[j], 0.0f) * di;
        hout[(size_t)node * NH + j] = o;
    }
}

// ---------------- Final: out = log_softmax(z2 @ W2 + b2) ----------------

__global__ void __launch_bounds__(256) k_out(const float* __restrict__ z2,
                                             const float* __restrict__ W2,
                                             const float* __restrict__ b2,
                                             float* __restrict__ out) {
    __shared__ float w[NH * NC];
    __shared__ float bb[NC];
    for (int i = threadIdx.x; i < NH * NC; i += 256) w[i] = W2[i];
    if (threadIdx.x < NC) bb[threadIdx.x] = b2[threadIdx.x];
    __syncthreads();
    int node = blockIdx.x * 256 + threadIdx.x;
    if (node >= NN) return;
    float z[NH];
    const f32x4* zp = (const f32x4*)(z2 + (size_t)node * NH);
#pragma unroll
    for (int q = 0; q < 4; ++q) {
        f32x4 v = zp[q];
        z[q * 4 + 0] = v.x; z[q * 4 + 1] = v.y; z[q * 4 + 2] = v.z; z[q * 4 + 3] = v.w;
    }
    float logit[NC];
#pragma unroll
    for (int c = 0; c < NC; ++c) logit[c] = bb[c];
#pragma unroll
    for (int k = 0; k < NH; ++k) {
        float zv = z[k];
#pragma unroll
        for (int c = 0; c < NC; ++c) logit[c] += zv * w[k * NC + c];
    }
    float mx = logit[0];
#pragma unroll
    for (int c = 1; c < NC; ++c) mx = fmaxf(mx, logit[c]);
    float sum = 0.f;
#pragma unroll
    for (int c = 0; c < NC; ++c) sum += __expf(logit[c] - mx);
    float lse = mx + __logf(sum);
    float* op = out + (size_t)node * NC;
#pragma unroll
    for (int c = 0; c < NC; ++c) op[c] = logit[c] - lse;
}

// ---------------- launch ----------------

extern "C" void kernel_launch(void* const* d_in, const int* in_sizes, int n_in,
                              void* d_out, int out_size, void* d_ws, size_t ws_size,
                              hipStream_t stream) {
    const float* x  = (const float*)d_in[0];
    const int*   ei = (const int*)d_in[1];
    const float* W1 = (const float*)d_in[2];
    const float* b1 = (const float*)d_in[3];
    const float* W2 = (const float*)d_in[4];
    const float* b2 = (const float*)d_in[5];
    float* out = (float*)d_out;

    char* ws = (char*)d_ws;
    size_t off = 0;
    auto alloc = [&](size_t bytes) -> void* {
        void* p = ws + off;
        off += (bytes + 255) & ~(size_t)255;
        return p;
    };
    int* histG      = (int*)alloc((size_t)NBLK * NB * 4);
    int* ofsG       = (int*)alloc((size_t)NB * NBLK * 4);
    int* bcnt       = (int*)alloc((size_t)NB * 4);
    int* bptr       = (int*)alloc((size_t)(NB + 1) * 4);
    int* rowptr     = (int*)alloc((size_t)(NN + 1) * 4);
    float* dinv     = (float*)alloc((size_t)NN * 4);
    unsigned short* w1p = (unsigned short*)alloc(16 * 64 * 8 * 2);
    unsigned int* pairs = (unsigned int*)alloc((size_t)NE * 4);
    int* ssrc       = (int*)alloc((size_t)NE * 4);
    float* h1       = (float*)alloc((size_t)NN * NH * 4);   // hs1, reused as z2
    float* r1       = (float*)alloc((size_t)NN * NH * 4);

    int nb = (NN + 255) / 256;          // 391

    k_packW1<<<32, 256, 0, stream>>>(W1, w1p);
    k_mshist<<<NBLK, 256, 0, stream>>>(ei, histG);
    k_colscan<<<NB, NBLK, 0, stream>>>(histG, ofsG, bcnt);
    k_bscan<<<1, 1024, 0, stream>>>(bcnt, bptr, rowptr);
    k_msscatter<<<NBLK, 256, 0, stream>>>(ei, bptr, ofsG, pairs);
    k_bsort<<<NB, 256, 0, stream>>>(pairs, bptr, rowptr, dinv, ssrc);
    k_gemm1<<<(NN + 63) / 64, 256, 0, stream>>>(x, w1p, dinv, h1);
    k_agg<<<NN / 4, 256, 0, stream>>>(h1, rowptr, ssrc, dinv, b1, r1, 1);
    k_agg<<<NN / 4, 256, 0, stream>>>(r1, rowptr, ssrc, dinv, nullptr, h1, 0);
    k_out<<<nb, 256, 0, stream>>>(h1, W2, b2, out);
}